// Round 3
// baseline (13891.991 us; speedup 1.0000x reference)
//
#include <hip/hip_runtime.h>

// Problem constants
#define T_STEPS 512
#define B_TOTAL 2048
#define IN_DIM  60
#define H_DIM   128
#define BPB     8      // batch rows per block
#define NTHR    512

// Workspace layout (float offsets). Weights repacked as [K/4][512] float4:
// WT4[k4][j] = {W[j][4k4], W[j][4k4+1], W[j][4k4+2], W[j][4k4+3]}
#define OFF_WT0X 0          // 15*512*4 = 30720 floats
#define OFF_WT0H 30720      // 32*512*4 = 65536
#define OFF_WT1X 96256      // 65536
#define OFF_WT1H 161792     // 65536
#define OFF_B0   227328     // 512 (bx0+bh0)
#define OFF_B1   227840     // 512 (bx1+bh1)

__device__ __forceinline__ float sigf(float v) {
    return 1.0f / (1.0f + __expf(-v));
}
__device__ __forceinline__ float tanh_fast(float v) {
    float a = fabsf(v);
    float e = __expf(-2.0f * a);            // in (0,1], no overflow
    float t = (1.0f - e) / (1.0f + e);
    return copysignf(t, v);
}
__device__ __forceinline__ void fma4(float& acc, const float4& wv, const float4& vv) {
    acc = fmaf(wv.x, vv.x, acc);
    acc = fmaf(wv.y, vv.y, acc);
    acc = fmaf(wv.z, vv.z, acc);
    acc = fmaf(wv.w, vv.w, acc);
}

__global__ void pack_kernel(const float* __restrict__ Wx0, const float* __restrict__ bx0,
                            const float* __restrict__ Wh0, const float* __restrict__ bh0,
                            const float* __restrict__ Wx1, const float* __restrict__ bx1,
                            const float* __restrict__ Wh1, const float* __restrict__ bh1,
                            float* __restrict__ ws) {
    int i = blockIdx.x * blockDim.x + threadIdx.x;
    if (i < 30720) {                       // Wx0: [512][60]
        int j = i / 60, k = i - j * 60;
        ws[OFF_WT0X + (k >> 2) * 2048 + (j << 2) + (k & 3)] = Wx0[i];
    } else if (i < 96256) {                // Wh0: [512][128]
        int e = i - 30720;
        int j = e >> 7, k = e & 127;
        ws[OFF_WT0H + (k >> 2) * 2048 + (j << 2) + (k & 3)] = Wh0[e];
    } else if (i < 161792) {               // Wx1: [512][128]
        int e = i - 96256;
        int j = e >> 7, k = e & 127;
        ws[OFF_WT1X + (k >> 2) * 2048 + (j << 2) + (k & 3)] = Wx1[e];
    } else if (i < 227328) {               // Wh1: [512][128]
        int e = i - 161792;
        int j = e >> 7, k = e & 127;
        ws[OFF_WT1H + (k >> 2) * 2048 + (j << 2) + (k & 3)] = Wh1[e];
    } else if (i < 227840) {               // combined biases
        int j = i - 227328;
        ws[OFF_B0 + j] = bx0[j] + bh0[j];
        ws[OFF_B1 + j] = bx1[j] + bh1[j];
    }
}

// One K-sweep of a gate GEMM: thread owns columns {cp, 128+cp, 256+cp, 384+cp}
// (i/f/g/o for hidden unit cp) and rows {r0, r0+1}. SRC rows read as broadcast b128.
#define GATE_SWEEP(WT, SRC, N4)                                          \
    _Pragma("unroll 4")                                                  \
    for (int k4 = 0; k4 < (N4); ++k4) {                                  \
        const float4 wgi = (WT)[(k4 << 9) + cp];                         \
        const float4 wgf = (WT)[(k4 << 9) + 128 + cp];                   \
        const float4 wgg = (WT)[(k4 << 9) + 256 + cp];                   \
        const float4 wgo = (WT)[(k4 << 9) + 384 + cp];                   \
        const float4 v0 = *(const float4*)&(SRC)[r0][k4 << 2];           \
        const float4 v1 = *(const float4*)&(SRC)[r0 + 1][k4 << 2];       \
        fma4(ai[0], wgi, v0); fma4(af[0], wgf, v0);                      \
        fma4(ag[0], wgg, v0); fma4(ao[0], wgo, v0);                      \
        fma4(ai[1], wgi, v1); fma4(af[1], wgf, v1);                      \
        fma4(ag[1], wgg, v1); fma4(ao[1], wgo, v1);                      \
    }

__global__ __launch_bounds__(NTHR) void lstm_fused(
    const float* __restrict__ x,
    const float* __restrict__ ws,
    const float* __restrict__ Wfc,
    const float* __restrict__ bfc,
    float* __restrict__ out)
{
    __shared__ float xs[BPB][64];          // x_t rows (60 used, pad for 16B align)
    __shared__ float h0s[BPB][H_DIM];
    __shared__ float h1s[BPB][H_DIM];
    __shared__ float b0s[4 * H_DIM];
    __shared__ float b1s[4 * H_DIM];

    const int tid = threadIdx.x;
    const int brow = blockIdx.x * BPB;

    const float4* __restrict__ WT0x = (const float4*)(ws + OFF_WT0X);
    const float4* __restrict__ WT0h = (const float4*)(ws + OFF_WT0H);
    const float4* __restrict__ WT1x = (const float4*)(ws + OFF_WT1X);
    const float4* __restrict__ WT1h = (const float4*)(ws + OFF_WT1H);

    b0s[tid] = ws[OFF_B0 + tid];
    b1s[tid] = ws[OFF_B1 + tid];
    for (int i = tid; i < BPB * H_DIM; i += NTHR) {
        (&h0s[0][0])[i] = 0.0f;
        (&h1s[0][0])[i] = 0.0f;
    }

    const int rg = tid >> 7;       // row group 0..3 (wave-uniform)
    const int r0 = rg << 1;        // rows r0, r0+1
    const int cp = tid & 127;      // hidden-unit column 0..127

    float c0[2] = {0.0f, 0.0f};
    float c1[2] = {0.0f, 0.0f};

    __syncthreads();

    for (int t = 0; t < T_STEPS; ++t) {
        // ---- stage x_t (480 floats) ----
        if (tid < BPB * IN_DIM) {
            int r = tid / IN_DIM;
            int k = tid - r * IN_DIM;
            xs[r][k] = x[((size_t)(brow + r) * T_STEPS + (size_t)t) * IN_DIM + k];
        }
        __syncthreads();                       // BAR1: xs ready; prev h1s writes visible

        // ---- layer 0 gates ----
        float ai[2], af[2], ag[2], ao[2];
        ai[0] = ai[1] = b0s[cp];
        af[0] = af[1] = b0s[128 + cp];
        ag[0] = ag[1] = b0s[256 + cp];
        ao[0] = ao[1] = b0s[384 + cp];
        GATE_SWEEP(WT0x, xs, 15);
        GATE_SWEEP(WT0h, h0s, 32);
        __syncthreads();                       // BAR2a: all h0s/xs reads done

        // ---- layer 0 cell update (in registers) ----
        #pragma unroll
        for (int rr = 0; rr < 2; ++rr) {
            float ii = sigf(ai[rr]);
            float ff = sigf(af[rr]);
            float gg = tanh_fast(ag[rr]);
            float oo = sigf(ao[rr]);
            c0[rr] = ff * c0[rr] + ii * gg;
            h0s[r0 + rr][cp] = oo * tanh_fast(c0[rr]);
        }
        __syncthreads();                       // BAR2b: new h0 visible

        // ---- layer 1 gates ----
        ai[0] = ai[1] = b1s[cp];
        af[0] = af[1] = b1s[128 + cp];
        ag[0] = ag[1] = b1s[256 + cp];
        ao[0] = ao[1] = b1s[384 + cp];
        GATE_SWEEP(WT1x, h0s, 32);
        GATE_SWEEP(WT1h, h1s, 32);
        __syncthreads();                       // BAR3a: all h1s reads done

        // ---- layer 1 cell update ----
        #pragma unroll
        for (int rr = 0; rr < 2; ++rr) {
            float ii = sigf(ai[rr]);
            float ff = sigf(af[rr]);
            float gg = tanh_fast(ag[rr]);
            float oo = sigf(ao[rr]);
            c1[rr] = ff * c1[rr] + ii * gg;
            h1s[r0 + rr][cp] = oo * tanh_fast(c1[rr]);
        }
        // next-iteration BAR1 separates these writes from layer-1 reads
    }
    __syncthreads();

    // ---- final FC: out[b] = h1[b,:] . Wfc + bfc ----
    if (tid < BPB) {
        float acc = bfc[0];
        #pragma unroll 8
        for (int n = 0; n < H_DIM; ++n)
            acc = fmaf(h1s[tid][n], Wfc[n], acc);
        out[brow + tid] = acc;
    }
}

extern "C" void kernel_launch(void* const* d_in, const int* in_sizes, int n_in,
                              void* d_out, int out_size, void* d_ws, size_t ws_size,
                              hipStream_t stream) {
    const float* xin = (const float*)d_in[0];
    const float* Wx0 = (const float*)d_in[1];
    const float* bx0 = (const float*)d_in[2];
    const float* Wh0 = (const float*)d_in[3];
    const float* bh0 = (const float*)d_in[4];
    const float* Wx1 = (const float*)d_in[5];
    const float* bx1 = (const float*)d_in[6];
    const float* Wh1 = (const float*)d_in[7];
    const float* bh1 = (const float*)d_in[8];
    const float* Wfc = (const float*)d_in[9];
    const float* bfc = (const float*)d_in[10];
    float* out = (float*)d_out;
    float* ws  = (float*)d_ws;

    pack_kernel<<<(227840 + 255) / 256, 256, 0, stream>>>(
        Wx0, bx0, Wh0, bh0, Wx1, bx1, Wh1, bh1, ws);
    lstm_fused<<<B_TOTAL / BPB, NTHR, 0, stream>>>(xin, ws, Wfc, bfc, out);
}